// Round 4
// baseline (390.187 us; speedup 1.0000x reference)
//
#include <hip/hip_runtime.h>

#define BN 131072   // B*N nodes
#define BE 2097152  // edges
#define NGR 64      // graphs
#define NPG 2048    // nodes per graph

// ws layout (bytes):
//   0        Xs    [64][16][64] f          (262144)
//   262144   wacc  [64][16] f              (4096)
//   266240   A     [64][16][16] f          (65536)   -> small region ends 331776
//   331776   start2[131072] int            (524288)  exclusive prefix; post-scatter = segment ends
//   856064   Sg    [131072][16] f          (8388608)
//   9244672  se1   [2097152] u32           (8388608) ; cnt2[131072] overlays its first 512KB
#define SMALL_ZERO_BYTES 331776
#define START2_OFF 331776
#define SG_OFF     856064
#define SE1_OFF    9244672

// ---------------- node kernel: S = softmax(x@Wa+ba); accumulate Xs, w ----------
__global__ __launch_bounds__(128) void k_node(const float* __restrict__ x,
                                              const float* __restrict__ Wa,
                                              const float* __restrict__ ba,
                                              float* __restrict__ Sg,
                                              float* __restrict__ Xs,
                                              float* __restrict__ wacc)
{
    __shared__ __align__(16) float Xl[128 * 65];   // stride 65
    __shared__ __align__(16) float Sl[128 * 20];   // stride 20 (float4-aligned)
    __shared__ float Wl[64 * 16];

    const int t = threadIdx.x;
    const int blk = blockIdx.x;       // 1024 blocks, 128 nodes each
    const int g = blk >> 4;           // 16 blocks per graph

    const float4* xg4 = (const float4*)(x + (size_t)blk * 128 * 64);
    #pragma unroll
    for (int it = 0; it < 16; ++it) {
        int idx4 = it * 128 + t;
        float4 v = xg4[idx4];
        int node = idx4 >> 4;
        int c4 = (idx4 & 15) * 4;
        float* p = &Xl[node * 65 + c4];
        p[0] = v.x; p[1] = v.y; p[2] = v.z; p[3] = v.w;
    }
    for (int i = t; i < 1024; i += 128) Wl[i] = Wa[i];
    __syncthreads();

    float lg[16];
    #pragma unroll
    for (int m = 0; m < 16; ++m) lg[m] = ba[m];
    for (int c = 0; c < 64; ++c) {
        float xc = Xl[t * 65 + c];
        #pragma unroll
        for (int m = 0; m < 16; ++m) lg[m] += xc * Wl[c * 16 + m];
    }
    float mx = lg[0];
    #pragma unroll
    for (int m = 1; m < 16; ++m) mx = fmaxf(mx, lg[m]);
    float s[16]; float sum = 0.f;
    #pragma unroll
    for (int m = 0; m < 16; ++m) { s[m] = expf(lg[m] - mx); sum += s[m]; }
    float inv = 1.f / sum;
    #pragma unroll
    for (int m = 0; m < 16; ++m) s[m] *= inv;

    float* srow = Sg + ((size_t)blk * 128 + t) * 16;
    #pragma unroll
    for (int q = 0; q < 4; ++q) {
        float4 v4 = make_float4(s[q*4], s[q*4+1], s[q*4+2], s[q*4+3]);
        *(float4*)(srow + q * 4) = v4;
        *(float4*)(&Sl[t * 20 + q * 4]) = v4;
    }
    __syncthreads();

    const int c = t & 63;
    const int half = t >> 6;
    float acc[8];
    #pragma unroll
    for (int j = 0; j < 8; ++j) acc[j] = 0.f;
    for (int n = 0; n < 128; ++n) {
        float xv = Xl[n * 65 + c];
        float4 sa = *(const float4*)(&Sl[n * 20 + half * 8]);
        float4 sb = *(const float4*)(&Sl[n * 20 + half * 8 + 4]);
        acc[0] += sa.x * xv; acc[1] += sa.y * xv; acc[2] += sa.z * xv; acc[3] += sa.w * xv;
        acc[4] += sb.x * xv; acc[5] += sb.y * xv; acc[6] += sb.z * xv; acc[7] += sb.w * xv;
    }
    float* xsg = Xs + g * 1024;
    #pragma unroll
    for (int j = 0; j < 8; ++j) atomicAdd(&xsg[(half * 8 + j) * 64 + c], acc[j]);

    if (t < 16) {
        float ws_ = 0.f;
        for (int n = 0; n < 128; ++n) ws_ += Sl[n * 20 + t];
        atomicAdd(&wacc[g * 16 + t], ws_);
    }
}

// ---------------- edge histogram by e0 node (131072 bins, global atomics) ------
__global__ __launch_bounds__(256) void k_hist2(const int* __restrict__ e0, int* __restrict__ cnt2)
{
    size_t base = (size_t)blockIdx.x * 1024 + threadIdx.x;
    #pragma unroll
    for (int k = 0; k < 4; ++k) {
        int e = e0[base + k * 256];
        atomicAdd(&cnt2[e], 1);
    }
}

// ---------------- exclusive prefix over 131072 bins (1 block, 1024 thr) --------
__global__ __launch_bounds__(1024) void k_prefix2(const int* __restrict__ cnt2, int* __restrict__ start2)
{
    __shared__ int ps[1024];
    int t = threadIdx.x;
    int base = t * 128;
    int s = 0;
    for (int j = 0; j < 128; ++j) s += cnt2[base + j];
    ps[t] = s;
    __syncthreads();
    for (int off = 1; off < 1024; off <<= 1) {
        int v = (t >= off) ? ps[t - off] : 0;
        __syncthreads();
        ps[t] += v;
        __syncthreads();
    }
    int run = t ? ps[t - 1] : 0;
    for (int j = 0; j < 128; ++j) {
        int cv = cnt2[base + j];
        start2[base + j] = run;
        run += cv;
    }
}

// ---------------- scatter e1 sorted by e0; start2 becomes segment ENDS ---------
__global__ __launch_bounds__(256) void k_scatter2(const int* __restrict__ e_,
                                                  int* __restrict__ start2,
                                                  unsigned* __restrict__ se1)
{
    size_t base = (size_t)blockIdx.x * 1024 + threadIdx.x;
    #pragma unroll
    for (int k = 0; k < 4; ++k) {
        size_t i = base + k * 256;
        int e0 = e_[i];
        int e1 = e_[BE + i];
        int pos = atomicAdd(&start2[e0], 1);
        se1[pos] = (unsigned)e1;
    }
}

// ---------------- edge kernel: AS per 64-node chunk in regs->LDS, then S^T@AS --
__global__ __launch_bounds__(256) void k_edge(const unsigned* __restrict__ se1,
                                              const float* __restrict__ Sg,
                                              const int* __restrict__ endp,
                                              float* __restrict__ A)
{
    __shared__ __align__(16) float ASl[64 * 16];   // 4 KiB
    const int t = threadIdx.x;
    const int blk = blockIdx.x;           // 2048 blocks, 64 nodes each
    const int g = blk >> 5;               // 32 blocks per graph
    const int nbase = blk << 6;

    // ---- phase A: quad (4 lanes) per node; lane owns component quad c4 ----
    {
        const int q  = t >> 2;            // local node 0..63
        const int c4 = (t & 3) << 2;
        const int node = nbase + q;
        const int lo = node ? endp[node - 1] : 0;
        const int hi = endp[node];
        const float* __restrict__ SgB = Sg + c4;

        float a0 = 0.f, a1 = 0.f, a2 = 0.f, a3 = 0.f;
        float b0 = 0.f, b1 = 0.f, b2 = 0.f, b3 = 0.f;
        int i = lo;
        for (; i + 2 <= hi; i += 2) {
            unsigned ea = se1[i];
            unsigned eb = se1[i + 1];
            float4 va = *(const float4*)(SgB + ((size_t)ea << 4));
            float4 vb = *(const float4*)(SgB + ((size_t)eb << 4));
            a0 += va.x; a1 += va.y; a2 += va.z; a3 += va.w;
            b0 += vb.x; b1 += vb.y; b2 += vb.z; b3 += vb.w;
        }
        if (i < hi) {
            unsigned ea = se1[i];
            float4 va = *(const float4*)(SgB + ((size_t)ea << 4));
            a0 += va.x; a1 += va.y; a2 += va.z; a3 += va.w;
        }
        *(float4*)(&ASl[q * 16 + c4]) = make_float4(a0 + b0, a1 + b1, a2 + b2, a3 + b3);
    }
    __syncthreads();

    // ---- phase B: A[g][m][k] partial over these 64 nodes ----
    {
        const int m = t >> 4;             // 0..15
        const int k = t & 15;
        const float* __restrict__ SgM = Sg + ((size_t)nbase << 4) + m;
        float a = 0.f;
        #pragma unroll 4
        for (int i = 0; i < 64; ++i) {
            a += SgM[(size_t)i << 4] * ASl[i * 16 + k];
        }
        atomicAdd(&A[g * 256 + t], a);
    }
}

// ---------------- x_out: [Zp(3) | Zf(61)] per (g,m) row ------------------------
__global__ __launch_bounds__(256) void k_xout(const float* __restrict__ Xs,
                                              const float* __restrict__ wacc,
                                              const float* __restrict__ We,
                                              const float* __restrict__ be,
                                              float* __restrict__ out)
{
    int t = threadIdx.x;
    int lane = t & 63;
    int row = blockIdx.x * 4 + (t >> 6);  // 0..1023
    const float* xs = Xs + row * 64;
    float w = wacc[row];
    float val;
    if (lane < 3) {
        val = xs[lane] / fmaxf(w, 1e-10f);
    } else {
        int c2 = lane - 3;
        float accv = w * be[c2];
        for (int cc = 0; cc < 64; ++cc) accv += xs[cc] * We[cc * 61 + c2];
        val = accv;
    }
    out[row * 64 + lane] = val;
}

// ---------------- top-k(4) of A_MM rows -> e_out, b_out ------------------------
__global__ __launch_bounds__(256) void k_topk(const float* __restrict__ A, float* __restrict__ out)
{
    int r = blockIdx.x * 256 + threadIdx.x;   // 0..1023  (= g*16 + m)
    float v[16];
    #pragma unroll
    for (int i = 0; i < 16; ++i) v[i] = A[r * 16 + i];
    float* e0o = out + 65536;
    float* e1o = out + 65536 + 4096;
    float* bo  = out + 65536 + 8192;
    unsigned mask = 0;
    #pragma unroll
    for (int rep = 0; rep < 4; ++rep) {
        float best = -3.4e38f; int bi = 0;
        #pragma unroll
        for (int i = 0; i < 16; ++i) {
            bool ok = (((mask >> i) & 1u) == 0u) && (v[i] > best);
            if (ok) { best = v[i]; bi = i; }
        }
        mask |= (1u << bi);
        e0o[r * 4 + rep] = (float)r;                       // src + offset == row index
        e1o[r * 4 + rep] = (float)((r & ~15) + bi);        // dst + g*16
    }
    bo[r] = (float)(r >> 4);
}

extern "C" void kernel_launch(void* const* d_in, const int* in_sizes, int n_in,
                              void* d_out, int out_size, void* d_ws, size_t ws_size,
                              hipStream_t stream)
{
    const float* x  = (const float*)d_in[0];
    const int*   e  = (const int*)d_in[1];
    const float* Wa = (const float*)d_in[3];
    const float* ba = (const float*)d_in[4];
    const float* We = (const float*)d_in[5];
    const float* be = (const float*)d_in[6];

    char* ws = (char*)d_ws;
    float* Xs     = (float*)ws;
    float* wacc   = (float*)(ws + 262144);
    float* A      = (float*)(ws + 266240);
    int*   start2 = (int*)(ws + START2_OFF);
    float* Sg     = (float*)(ws + SG_OFF);
    unsigned* se1 = (unsigned*)(ws + SE1_OFF);
    int*   cnt2   = (int*)(ws + SE1_OFF);   // overlays se1's first 512KB (dead before se1 written)

    hipMemsetAsync(ws, 0, SMALL_ZERO_BYTES, stream);                 // Xs, wacc, A
    hipMemsetAsync(ws + SE1_OFF, 0, 131072 * sizeof(int), stream);   // cnt2
    k_node    <<<1024, 128, 0, stream>>>(x, Wa, ba, Sg, Xs, wacc);
    k_hist2   <<<2048, 256, 0, stream>>>(e, cnt2);
    k_prefix2 <<<1, 1024, 0, stream>>>(cnt2, start2);
    k_scatter2<<<2048, 256, 0, stream>>>(e, start2, se1);
    k_edge    <<<2048, 256, 0, stream>>>(se1, Sg, start2, A);
    k_xout    <<<256, 256, 0, stream>>>(Xs, wacc, We, be, (float*)d_out);
    k_topk    <<<4, 256, 0, stream>>>(A, (float*)d_out);
}

// Round 5
// 151.418 us; speedup vs baseline: 2.5769x; 2.5769x over previous
//
#include <hip/hip_runtime.h>

#define BN 131072   // B*N nodes
#define BE 2097152  // edges
#define NGR 64      // graphs

// ws layout (bytes):
#define XS_OFF     0          // Xs   [64][16][64] f   = 262144
#define WACC_OFF   262144     // wacc [64][16] f       = 4096
#define A_OFF      266240     // A    [64][16][16] f   = 65536  -> 331776
#define CNTG_OFF   331776     // cntG   [64] int
#define STARTG_OFF 332032     // startG [64] int
#define CURSG_OFF  332288     // cursorG[64] int
#define QS_OFF     332544     // qs    [256] int       -> 333568
#define META_ZERO  333568
#define ENDS_OFF   333568     // ends4 [256][2048] int = 2097152 -> 2430720
#define SG_OFF     2430720    // Sg [131072][16] f     = 8388608 -> 10819328
#define PK_OFF     10819328   // packed [2097152] u32  = 8388608 (sorted in place)

// ---------------- node kernel: S = softmax(x@Wa+ba); accumulate Xs, w ----------
__global__ __launch_bounds__(128) void k_node(const float* __restrict__ x,
                                              const float* __restrict__ Wa,
                                              const float* __restrict__ ba,
                                              float* __restrict__ Sg,
                                              float* __restrict__ Xs,
                                              float* __restrict__ wacc)
{
    __shared__ __align__(16) float Xl[128 * 65];
    __shared__ __align__(16) float Sl[128 * 20];
    __shared__ float Wl[64 * 16];

    const int t = threadIdx.x;
    const int blk = blockIdx.x;       // 1024 blocks, 128 nodes each
    const int g = blk >> 4;

    const float4* xg4 = (const float4*)(x + (size_t)blk * 128 * 64);
    #pragma unroll
    for (int it = 0; it < 16; ++it) {
        int idx4 = it * 128 + t;
        float4 v = xg4[idx4];
        int node = idx4 >> 4;
        int c4 = (idx4 & 15) * 4;
        float* p = &Xl[node * 65 + c4];
        p[0] = v.x; p[1] = v.y; p[2] = v.z; p[3] = v.w;
    }
    for (int i = t; i < 1024; i += 128) Wl[i] = Wa[i];
    __syncthreads();

    float lg[16];
    #pragma unroll
    for (int m = 0; m < 16; ++m) lg[m] = ba[m];
    for (int c = 0; c < 64; ++c) {
        float xc = Xl[t * 65 + c];
        #pragma unroll
        for (int m = 0; m < 16; ++m) lg[m] += xc * Wl[c * 16 + m];
    }
    float mx = lg[0];
    #pragma unroll
    for (int m = 1; m < 16; ++m) mx = fmaxf(mx, lg[m]);
    float s[16]; float sum = 0.f;
    #pragma unroll
    for (int m = 0; m < 16; ++m) { s[m] = expf(lg[m] - mx); sum += s[m]; }
    float inv = 1.f / sum;
    #pragma unroll
    for (int m = 0; m < 16; ++m) s[m] *= inv;

    float* srow = Sg + ((size_t)blk * 128 + t) * 16;
    #pragma unroll
    for (int q = 0; q < 4; ++q) {
        float4 v4 = make_float4(s[q*4], s[q*4+1], s[q*4+2], s[q*4+3]);
        *(float4*)(srow + q * 4) = v4;
        *(float4*)(&Sl[t * 20 + q * 4]) = v4;
    }
    __syncthreads();

    const int c = t & 63;
    const int half = t >> 6;
    float acc[8];
    #pragma unroll
    for (int j = 0; j < 8; ++j) acc[j] = 0.f;
    for (int n = 0; n < 128; ++n) {
        float xv = Xl[n * 65 + c];
        float4 sa = *(const float4*)(&Sl[n * 20 + half * 8]);
        float4 sb = *(const float4*)(&Sl[n * 20 + half * 8 + 4]);
        acc[0] += sa.x * xv; acc[1] += sa.y * xv; acc[2] += sa.z * xv; acc[3] += sa.w * xv;
        acc[4] += sb.x * xv; acc[5] += sb.y * xv; acc[6] += sb.z * xv; acc[7] += sb.w * xv;
    }
    float* xsg = Xs + g * 1024;
    #pragma unroll
    for (int j = 0; j < 8; ++j) atomicAdd(&xsg[(half * 8 + j) * 64 + c], acc[j]);

    if (t < 16) {
        float ws_ = 0.f;
        for (int n = 0; n < 128; ++n) ws_ += Sl[n * 20 + t];
        atomicAdd(&wacc[g * 16 + t], ws_);
    }
}

// ---------------- level-1: graph histogram (64 bins) ---------------------------
__global__ __launch_bounds__(256) void k_histG(const int* __restrict__ e0, int* __restrict__ cntG)
{
    __shared__ int h[64];
    int t = threadIdx.x;
    if (t < 64) h[t] = 0;
    __syncthreads();
    size_t base = (size_t)blockIdx.x * 2048;
    #pragma unroll
    for (int k = 0; k < 8; ++k) {
        int e = e0[base + k * 256 + t];
        atomicAdd(&h[e >> 11], 1);
    }
    __syncthreads();
    if (t < 64) atomicAdd(&cntG[t], h[t]);
}

__global__ void k_prefixG(const int* __restrict__ cntG, int* __restrict__ startG,
                          int* __restrict__ cursorG, int* __restrict__ qs)
{
    if (threadIdx.x == 0) {
        int s = 0;
        for (int g = 0; g < 64; ++g) {
            startG[g] = s; cursorG[g] = s;
            int n = cntG[g];
            int chunk = (n + 3) >> 2;
            for (int q = 0; q < 4; ++q) qs[g * 4 + q] = s + min(q * chunk, n);
            s += n;
        }
    }
}

// ---------------- level-1 scatter: graph-grouped packed (e0l<<17 | e1) ---------
__global__ __launch_bounds__(256) void k_scatterG(const int* __restrict__ e_,
                                                  int* __restrict__ cursorG,
                                                  unsigned* __restrict__ packed)
{
    __shared__ int h[64];
    __shared__ int gb[64];
    int t = threadIdx.x;
    if (t < 64) h[t] = 0;
    __syncthreads();
    size_t base = (size_t)blockIdx.x * 2048;
    int e0v[8], e1v[8], rk[8];
    #pragma unroll
    for (int k = 0; k < 8; ++k) {
        size_t i = base + k * 256 + t;
        e0v[k] = e_[i];
        e1v[k] = e_[BE + i];
        rk[k] = atomicAdd(&h[e0v[k] >> 11], 1);
    }
    __syncthreads();
    if (t < 64) gb[t] = atomicAdd(&cursorG[t], h[t]);
    __syncthreads();
    #pragma unroll
    for (int k = 0; k < 8; ++k) {
        int b = e0v[k] >> 11;
        packed[gb[b] + rk[k]] = ((unsigned)(e0v[k] & 2047) << 17) | (unsigned)e1v[k];
    }
}

// ---------------- level-2: LDS counting sort of each quarter-slab by e0l -------
#define SBUF_CAP 8704
__global__ __launch_bounds__(256) void k_sortL(unsigned* __restrict__ packed,
                                               const int* __restrict__ startG,
                                               const int* __restrict__ cntG,
                                               const int* __restrict__ qs,
                                               int* __restrict__ ends4)
{
    __shared__ unsigned sbuf[SBUF_CAP];
    __shared__ unsigned sout[SBUF_CAP];
    __shared__ int h[2048];
    __shared__ int psum[256];
    const int t = threadIdx.x;
    const int Q = blockIdx.x;                 // g*4+q
    const int qlo = qs[Q];
    const int qhi = (Q == 255) ? BE : qs[Q + 1];
    const int nq = qhi - qlo;

    for (int i = t; i < 2048; i += 256) h[i] = 0;
    __syncthreads();
    for (int i = t; i < nq; i += 256) {
        unsigned u = packed[qlo + i];
        sbuf[i] = u;
        atomicAdd(&h[u >> 17], 1);
    }
    __syncthreads();

    // block scan over 2048 bins: thread owns bins [t*8, t*8+8)
    int hl[8]; int s = 0;
    #pragma unroll
    for (int j = 0; j < 8; ++j) { hl[j] = h[t * 8 + j]; s += hl[j]; }
    psum[t] = s;
    __syncthreads();
    for (int off = 1; off < 256; off <<= 1) {
        int v = (t >= off) ? psum[t - off] : 0;
        __syncthreads();
        psum[t] += v;
        __syncthreads();
    }
    int run = psum[t] - s;    // exclusive start of this thread's bin range
    int* ends = ends4 + (Q << 11);
    #pragma unroll
    for (int j = 0; j < 8; ++j) {
        int bin = t * 8 + j;
        int c = hl[j];
        h[bin] = run;               // relative scatter cursor
        run += c;
        ends[bin] = qlo + run;      // inclusive global end pointer
    }
    __syncthreads();
    for (int i = t; i < nq; i += 256) {
        unsigned u = sbuf[i];
        int pos = atomicAdd(&h[u >> 17], 1);
        sout[pos] = u & 131071u;    // keep only e1
    }
    __syncthreads();
    for (int i = t; i < nq; i += 256) packed[qlo + i] = sout[i];  // coalesced
}

// ---------------- edge kernel: AS per 64-node chunk (regs->LDS), then S^T@AS ---
__global__ __launch_bounds__(256) void k_edge(const unsigned* __restrict__ se1,
                                              const float* __restrict__ Sg,
                                              const int* __restrict__ ends4,
                                              const int* __restrict__ qs,
                                              float* __restrict__ A)
{
    __shared__ __align__(16) float ASl[64 * 16];   // 4 KiB
    const int t = threadIdx.x;
    const int blk = blockIdx.x;           // 2048 blocks, 64 nodes each
    const int g = blk >> 5;
    const int nbase = blk << 6;

    {
        const int qd = t >> 2;            // local node 0..63
        const int c4 = (t & 3) << 2;
        const int nl = (nbase & 2047) + qd;
        const float* __restrict__ SgB = Sg + c4;
        float a0 = 0.f, a1 = 0.f, a2 = 0.f, a3 = 0.f;
        float b0 = 0.f, b1 = 0.f, b2 = 0.f, b3 = 0.f;
        #pragma unroll
        for (int q = 0; q < 4; ++q) {
            const int Qb = (g << 2) + q;
            const int* __restrict__ ends = ends4 + (Qb << 11);
            int lo = nl ? ends[nl - 1] : qs[Qb];
            int hi = ends[nl];
            int i = lo;
            for (; i + 2 <= hi; i += 2) {
                unsigned ea = se1[i];
                unsigned eb = se1[i + 1];
                float4 va = *(const float4*)(SgB + ((size_t)ea << 4));
                float4 vb = *(const float4*)(SgB + ((size_t)eb << 4));
                a0 += va.x; a1 += va.y; a2 += va.z; a3 += va.w;
                b0 += vb.x; b1 += vb.y; b2 += vb.z; b3 += vb.w;
            }
            if (i < hi) {
                unsigned ea = se1[i];
                float4 va = *(const float4*)(SgB + ((size_t)ea << 4));
                a0 += va.x; a1 += va.y; a2 += va.z; a3 += va.w;
            }
        }
        *(float4*)(&ASl[qd * 16 + c4]) = make_float4(a0 + b0, a1 + b1, a2 + b2, a3 + b3);
    }
    __syncthreads();

    {
        const int m = t >> 4;
        const int k = t & 15;
        const float* __restrict__ SgM = Sg + ((size_t)nbase << 4) + m;
        float a = 0.f;
        #pragma unroll 4
        for (int i = 0; i < 64; ++i) {
            a += SgM[(size_t)i << 4] * ASl[i * 16 + k];
        }
        atomicAdd(&A[(g << 8) + t], a);
    }
}

// ---------------- x_out: [Zp(3) | Zf(61)] per (g,m) row ------------------------
__global__ __launch_bounds__(256) void k_xout(const float* __restrict__ Xs,
                                              const float* __restrict__ wacc,
                                              const float* __restrict__ We,
                                              const float* __restrict__ be,
                                              float* __restrict__ out)
{
    int t = threadIdx.x;
    int lane = t & 63;
    int row = blockIdx.x * 4 + (t >> 6);  // 0..1023
    const float* xs = Xs + row * 64;
    float w = wacc[row];
    float val;
    if (lane < 3) {
        val = xs[lane] / fmaxf(w, 1e-10f);
    } else {
        int c2 = lane - 3;
        float accv = w * be[c2];
        for (int cc = 0; cc < 64; ++cc) accv += xs[cc] * We[cc * 61 + c2];
        val = accv;
    }
    out[row * 64 + lane] = val;
}

// ---------------- top-k(4) of A_MM rows -> e_out, b_out ------------------------
__global__ __launch_bounds__(256) void k_topk(const float* __restrict__ A, float* __restrict__ out)
{
    int r = blockIdx.x * 256 + threadIdx.x;   // 0..1023  (= g*16 + m)
    float v[16];
    #pragma unroll
    for (int i = 0; i < 16; ++i) v[i] = A[r * 16 + i];
    float* e0o = out + 65536;
    float* e1o = out + 65536 + 4096;
    float* bo  = out + 65536 + 8192;
    unsigned mask = 0;
    #pragma unroll
    for (int rep = 0; rep < 4; ++rep) {
        float best = -3.4e38f; int bi = 0;
        #pragma unroll
        for (int i = 0; i < 16; ++i) {
            bool ok = (((mask >> i) & 1u) == 0u) && (v[i] > best);
            if (ok) { best = v[i]; bi = i; }
        }
        mask |= (1u << bi);
        e0o[r * 4 + rep] = (float)r;
        e1o[r * 4 + rep] = (float)((r & ~15) + bi);
    }
    bo[r] = (float)(r >> 4);
}

extern "C" void kernel_launch(void* const* d_in, const int* in_sizes, int n_in,
                              void* d_out, int out_size, void* d_ws, size_t ws_size,
                              hipStream_t stream)
{
    const float* x  = (const float*)d_in[0];
    const int*   e  = (const int*)d_in[1];
    const float* Wa = (const float*)d_in[3];
    const float* ba = (const float*)d_in[4];
    const float* We = (const float*)d_in[5];
    const float* be = (const float*)d_in[6];

    char* ws = (char*)d_ws;
    float* Xs     = (float*)(ws + XS_OFF);
    float* wacc   = (float*)(ws + WACC_OFF);
    float* A      = (float*)(ws + A_OFF);
    int*   cntG   = (int*)(ws + CNTG_OFF);
    int*   startG = (int*)(ws + STARTG_OFF);
    int*   cursG  = (int*)(ws + CURSG_OFF);
    int*   qs     = (int*)(ws + QS_OFF);
    int*   ends4  = (int*)(ws + ENDS_OFF);
    float* Sg     = (float*)(ws + SG_OFF);
    unsigned* packed = (unsigned*)(ws + PK_OFF);

    hipMemsetAsync(ws, 0, META_ZERO, stream);
    k_node    <<<1024, 128, 0, stream>>>(x, Wa, ba, Sg, Xs, wacc);
    k_histG   <<<1024, 256, 0, stream>>>(e, cntG);
    k_prefixG <<<1, 64, 0, stream>>>(cntG, startG, cursG, qs);
    k_scatterG<<<1024, 256, 0, stream>>>(e, cursG, packed);
    k_sortL   <<<256, 256, 0, stream>>>(packed, startG, cntG, qs, ends4);
    k_edge    <<<2048, 256, 0, stream>>>(packed, Sg, ends4, qs, A);
    k_xout    <<<256, 256, 0, stream>>>(Xs, wacc, We, be, (float*)d_out);
    k_topk    <<<4, 256, 0, stream>>>(A, (float*)d_out);
}

// Round 6
// 150.368 us; speedup vs baseline: 2.5949x; 1.0070x over previous
//
#include <hip/hip_runtime.h>

#define BN 131072   // B*N nodes
#define BE 2097152  // edges
#define NGR 64      // graphs

// ws layout (bytes):
#define XS_OFF     0          // Xs   [64][16][64] f   = 262144
#define WACC_OFF   262144     // wacc [64][16] f       = 4096
#define A_OFF      266240     // A    [64][16][16] f   = 65536  -> 331776
#define CNTG_OFF   331776     // cntG   [64] int
#define STARTG_OFF 332032     // startG [64] int
#define CURSG_OFF  332288     // cursorG[64] int
#define QS_OFF     332544     // qs    [256] int       -> 333568
#define META_ZERO  333568
#define ENDS_OFF   333568     // ends4 [256][2048] int = 2097152 -> 2430720
#define SG_OFF     2430720    // Sg [131072][16] f     = 8388608 -> 10819328
#define PK_OFF     10819328   // packed [2097152] u32  = 8388608 (sorted in place)

// ---------------- zero the accumulator region (replaces slow rocclr fill) ------
// META_ZERO bytes = 20848 uint4
__global__ __launch_bounds__(256) void k_zero(uint4* __restrict__ p)
{
    int i = blockIdx.x * 256 + threadIdx.x;
    if (i < 20848) p[i] = make_uint4(0u, 0u, 0u, 0u);
}

// ---------------- node kernel: S = softmax(x@Wa+ba); accumulate Xs, w ----------
__global__ __launch_bounds__(128) void k_node(const float* __restrict__ x,
                                              const float* __restrict__ Wa,
                                              const float* __restrict__ ba,
                                              float* __restrict__ Sg,
                                              float* __restrict__ Xs,
                                              float* __restrict__ wacc)
{
    __shared__ __align__(16) float Xl[128 * 65];
    __shared__ __align__(16) float Sl[128 * 20];
    __shared__ float Wl[64 * 16];

    const int t = threadIdx.x;
    const int blk = blockIdx.x;       // 1024 blocks, 128 nodes each
    const int g = blk >> 4;

    const float4* xg4 = (const float4*)(x + (size_t)blk * 128 * 64);
    #pragma unroll
    for (int it = 0; it < 16; ++it) {
        int idx4 = it * 128 + t;
        float4 v = xg4[idx4];
        int node = idx4 >> 4;
        int c4 = (idx4 & 15) * 4;
        float* p = &Xl[node * 65 + c4];
        p[0] = v.x; p[1] = v.y; p[2] = v.z; p[3] = v.w;
    }
    for (int i = t; i < 1024; i += 128) Wl[i] = Wa[i];
    __syncthreads();

    float lg[16];
    #pragma unroll
    for (int m = 0; m < 16; ++m) lg[m] = ba[m];
    for (int c = 0; c < 64; ++c) {
        float xc = Xl[t * 65 + c];
        #pragma unroll
        for (int m = 0; m < 16; ++m) lg[m] += xc * Wl[c * 16 + m];
    }
    float mx = lg[0];
    #pragma unroll
    for (int m = 1; m < 16; ++m) mx = fmaxf(mx, lg[m]);
    float s[16]; float sum = 0.f;
    #pragma unroll
    for (int m = 0; m < 16; ++m) { s[m] = expf(lg[m] - mx); sum += s[m]; }
    float inv = 1.f / sum;
    #pragma unroll
    for (int m = 0; m < 16; ++m) s[m] *= inv;

    float* srow = Sg + ((size_t)blk * 128 + t) * 16;
    #pragma unroll
    for (int q = 0; q < 4; ++q) {
        float4 v4 = make_float4(s[q*4], s[q*4+1], s[q*4+2], s[q*4+3]);
        *(float4*)(srow + q * 4) = v4;
        *(float4*)(&Sl[t * 20 + q * 4]) = v4;
    }
    __syncthreads();

    const int c = t & 63;
    const int half = t >> 6;
    float acc[8];
    #pragma unroll
    for (int j = 0; j < 8; ++j) acc[j] = 0.f;
    for (int n = 0; n < 128; ++n) {
        float xv = Xl[n * 65 + c];
        float4 sa = *(const float4*)(&Sl[n * 20 + half * 8]);
        float4 sb = *(const float4*)(&Sl[n * 20 + half * 8 + 4]);
        acc[0] += sa.x * xv; acc[1] += sa.y * xv; acc[2] += sa.z * xv; acc[3] += sa.w * xv;
        acc[4] += sb.x * xv; acc[5] += sb.y * xv; acc[6] += sb.z * xv; acc[7] += sb.w * xv;
    }
    float* xsg = Xs + g * 1024;
    #pragma unroll
    for (int j = 0; j < 8; ++j) atomicAdd(&xsg[(half * 8 + j) * 64 + c], acc[j]);

    if (t < 16) {
        float ws_ = 0.f;
        for (int n = 0; n < 128; ++n) ws_ += Sl[n * 20 + t];
        atomicAdd(&wacc[g * 16 + t], ws_);
    }
}

// ---------------- level-1: graph histogram (64 bins) ---------------------------
__global__ __launch_bounds__(256) void k_histG(const int* __restrict__ e0, int* __restrict__ cntG)
{
    __shared__ int h[64];
    int t = threadIdx.x;
    if (t < 64) h[t] = 0;
    __syncthreads();
    size_t base = (size_t)blockIdx.x * 2048;
    #pragma unroll
    for (int k = 0; k < 8; ++k) {
        int e = e0[base + k * 256 + t];
        atomicAdd(&h[e >> 11], 1);
    }
    __syncthreads();
    if (t < 64) atomicAdd(&cntG[t], h[t]);
}

__global__ void k_prefixG(const int* __restrict__ cntG, int* __restrict__ startG,
                          int* __restrict__ cursorG, int* __restrict__ qs)
{
    if (threadIdx.x == 0) {
        int s = 0;
        for (int g = 0; g < 64; ++g) {
            startG[g] = s; cursorG[g] = s;
            int n = cntG[g];
            int chunk = (n + 3) >> 2;
            for (int q = 0; q < 4; ++q) qs[g * 4 + q] = s + min(q * chunk, n);
            s += n;
        }
    }
}

// ---------------- level-1 scatter: graph-grouped packed (e0l<<17 | e1) ---------
__global__ __launch_bounds__(256) void k_scatterG(const int* __restrict__ e_,
                                                  int* __restrict__ cursorG,
                                                  unsigned* __restrict__ packed)
{
    __shared__ int h[64];
    __shared__ int gb[64];
    int t = threadIdx.x;
    if (t < 64) h[t] = 0;
    __syncthreads();
    size_t base = (size_t)blockIdx.x * 2048;
    int e0v[8], e1v[8], rk[8];
    #pragma unroll
    for (int k = 0; k < 8; ++k) {
        size_t i = base + k * 256 + t;
        e0v[k] = e_[i];
        e1v[k] = e_[BE + i];
        rk[k] = atomicAdd(&h[e0v[k] >> 11], 1);
    }
    __syncthreads();
    if (t < 64) gb[t] = atomicAdd(&cursorG[t], h[t]);
    __syncthreads();
    #pragma unroll
    for (int k = 0; k < 8; ++k) {
        int b = e0v[k] >> 11;
        packed[gb[b] + rk[k]] = ((unsigned)(e0v[k] & 2047) << 17) | (unsigned)e1v[k];
    }
}

// ---------------- level-2: LDS counting sort of each quarter-slab by e0l -------
#define SBUF_CAP 8704
__global__ __launch_bounds__(256) void k_sortL(unsigned* __restrict__ packed,
                                               const int* __restrict__ startG,
                                               const int* __restrict__ cntG,
                                               const int* __restrict__ qs,
                                               int* __restrict__ ends4)
{
    __shared__ unsigned sbuf[SBUF_CAP];
    __shared__ unsigned sout[SBUF_CAP];
    __shared__ int h[2048];
    __shared__ int psum[256];
    const int t = threadIdx.x;
    const int Q = blockIdx.x;                 // g*4+q
    const int qlo = qs[Q];
    const int qhi = (Q == 255) ? BE : qs[Q + 1];
    const int nq = qhi - qlo;

    for (int i = t; i < 2048; i += 256) h[i] = 0;
    __syncthreads();
    for (int i = t; i < nq; i += 256) {
        unsigned u = packed[qlo + i];
        sbuf[i] = u;
        atomicAdd(&h[u >> 17], 1);
    }
    __syncthreads();

    // block scan over 2048 bins: thread owns bins [t*8, t*8+8)
    int hl[8]; int s = 0;
    #pragma unroll
    for (int j = 0; j < 8; ++j) { hl[j] = h[t * 8 + j]; s += hl[j]; }
    psum[t] = s;
    __syncthreads();
    for (int off = 1; off < 256; off <<= 1) {
        int v = (t >= off) ? psum[t - off] : 0;
        __syncthreads();
        psum[t] += v;
        __syncthreads();
    }
    int run = psum[t] - s;    // exclusive start of this thread's bin range
    int* ends = ends4 + (Q << 11);
    #pragma unroll
    for (int j = 0; j < 8; ++j) {
        int bin = t * 8 + j;
        int c = hl[j];
        h[bin] = run;               // relative scatter cursor
        run += c;
        ends[bin] = qlo + run;      // inclusive global end pointer
    }
    __syncthreads();
    for (int i = t; i < nq; i += 256) {
        unsigned u = sbuf[i];
        int pos = atomicAdd(&h[u >> 17], 1);
        sout[pos] = u & 131071u;    // keep only e1
    }
    __syncthreads();
    for (int i = t; i < nq; i += 256) packed[qlo + i] = sout[i];  // coalesced
}

// ---------------- edge kernel: AS per 64-node chunk (regs->LDS), then S^T@AS ---
__global__ __launch_bounds__(256) void k_edge(const unsigned* __restrict__ se1,
                                              const float* __restrict__ Sg,
                                              const int* __restrict__ ends4,
                                              const int* __restrict__ qs,
                                              float* __restrict__ A)
{
    __shared__ __align__(16) float ASl[64 * 16];   // 4 KiB
    const int t = threadIdx.x;
    const int blk = blockIdx.x;           // 2048 blocks, 64 nodes each
    const int g = blk >> 5;
    const int nbase = blk << 6;

    {
        const int qd = t >> 2;            // local node 0..63
        const int c4 = (t & 3) << 2;
        const int nl = (nbase & 2047) + qd;
        const float* __restrict__ SgB = Sg + c4;
        float a0 = 0.f, a1 = 0.f, a2 = 0.f, a3 = 0.f;
        float b0 = 0.f, b1 = 0.f, b2 = 0.f, b3 = 0.f;
        #pragma unroll
        for (int q = 0; q < 4; ++q) {
            const int Qb = (g << 2) + q;
            const int* __restrict__ ends = ends4 + (Qb << 11);
            int lo = nl ? ends[nl - 1] : qs[Qb];
            int hi = ends[nl];
            int i = lo;
            for (; i + 2 <= hi; i += 2) {
                unsigned ea = se1[i];
                unsigned eb = se1[i + 1];
                float4 va = *(const float4*)(SgB + ((size_t)ea << 4));
                float4 vb = *(const float4*)(SgB + ((size_t)eb << 4));
                a0 += va.x; a1 += va.y; a2 += va.z; a3 += va.w;
                b0 += vb.x; b1 += vb.y; b2 += vb.z; b3 += vb.w;
            }
            if (i < hi) {
                unsigned ea = se1[i];
                float4 va = *(const float4*)(SgB + ((size_t)ea << 4));
                a0 += va.x; a1 += va.y; a2 += va.z; a3 += va.w;
            }
        }
        *(float4*)(&ASl[qd * 16 + c4]) = make_float4(a0 + b0, a1 + b1, a2 + b2, a3 + b3);
    }
    __syncthreads();

    {
        const int m = t >> 4;
        const int k = t & 15;
        const float* __restrict__ SgM = Sg + ((size_t)nbase << 4) + m;
        float a = 0.f;
        #pragma unroll 4
        for (int i = 0; i < 64; ++i) {
            a += SgM[(size_t)i << 4] * ASl[i * 16 + k];
        }
        atomicAdd(&A[(g << 8) + t], a);
    }
}

// ---------------- x_out: [Zp(3) | Zf(61)] per (g,m) row ------------------------
__global__ __launch_bounds__(256) void k_xout(const float* __restrict__ Xs,
                                              const float* __restrict__ wacc,
                                              const float* __restrict__ We,
                                              const float* __restrict__ be,
                                              float* __restrict__ out)
{
    int t = threadIdx.x;
    int lane = t & 63;
    int row = blockIdx.x * 4 + (t >> 6);  // 0..1023
    const float* xs = Xs + row * 64;
    float w = wacc[row];
    float val;
    if (lane < 3) {
        val = xs[lane] / fmaxf(w, 1e-10f);
    } else {
        int c2 = lane - 3;
        float accv = w * be[c2];
        for (int cc = 0; cc < 64; ++cc) accv += xs[cc] * We[cc * 61 + c2];
        val = accv;
    }
    out[row * 64 + lane] = val;
}

// ---------------- top-k(4) of A_MM rows -> e_out, b_out ------------------------
__global__ __launch_bounds__(256) void k_topk(const float* __restrict__ A, float* __restrict__ out)
{
    int r = blockIdx.x * 256 + threadIdx.x;   // 0..1023  (= g*16 + m)
    float v[16];
    #pragma unroll
    for (int i = 0; i < 16; ++i) v[i] = A[r * 16 + i];
    float* e0o = out + 65536;
    float* e1o = out + 65536 + 4096;
    float* bo  = out + 65536 + 8192;
    unsigned mask = 0;
    #pragma unroll
    for (int rep = 0; rep < 4; ++rep) {
        float best = -3.4e38f; int bi = 0;
        #pragma unroll
        for (int i = 0; i < 16; ++i) {
            bool ok = (((mask >> i) & 1u) == 0u) && (v[i] > best);
            if (ok) { best = v[i]; bi = i; }
        }
        mask |= (1u << bi);
        e0o[r * 4 + rep] = (float)r;
        e1o[r * 4 + rep] = (float)((r & ~15) + bi);
    }
    bo[r] = (float)(r >> 4);
}

extern "C" void kernel_launch(void* const* d_in, const int* in_sizes, int n_in,
                              void* d_out, int out_size, void* d_ws, size_t ws_size,
                              hipStream_t stream)
{
    const float* x  = (const float*)d_in[0];
    const int*   e  = (const int*)d_in[1];
    const float* Wa = (const float*)d_in[3];
    const float* ba = (const float*)d_in[4];
    const float* We = (const float*)d_in[5];
    const float* be = (const float*)d_in[6];

    char* ws = (char*)d_ws;
    float* Xs     = (float*)(ws + XS_OFF);
    float* wacc   = (float*)(ws + WACC_OFF);
    float* A      = (float*)(ws + A_OFF);
    int*   cntG   = (int*)(ws + CNTG_OFF);
    int*   startG = (int*)(ws + STARTG_OFF);
    int*   cursG  = (int*)(ws + CURSG_OFF);
    int*   qs     = (int*)(ws + QS_OFF);
    int*   ends4  = (int*)(ws + ENDS_OFF);
    float* Sg     = (float*)(ws + SG_OFF);
    unsigned* packed = (unsigned*)(ws + PK_OFF);

    k_zero    <<<82, 256, 0, stream>>>((uint4*)ws);
    k_node    <<<1024, 128, 0, stream>>>(x, Wa, ba, Sg, Xs, wacc);
    k_histG   <<<1024, 256, 0, stream>>>(e, cntG);
    k_prefixG <<<1, 64, 0, stream>>>(cntG, startG, cursG, qs);
    k_scatterG<<<1024, 256, 0, stream>>>(e, cursG, packed);
    k_sortL   <<<256, 256, 0, stream>>>(packed, startG, cntG, qs, ends4);
    k_edge    <<<2048, 256, 0, stream>>>(packed, Sg, ends4, qs, A);
    k_xout    <<<256, 256, 0, stream>>>(Xs, wacc, We, be, (float*)d_out);
    k_topk    <<<4, 256, 0, stream>>>(A, (float*)d_out);
}

// Round 7
// 118.745 us; speedup vs baseline: 3.2859x; 1.2663x over previous
//
#include <hip/hip_runtime.h>

#define BN 131072   // B*N nodes
#define BE 2097152  // edges
#define NGR 64      // graphs

// ws layout (bytes):
#define XS_OFF     0          // Xs   [64][16][64] f   = 262144
#define WACC_OFF   262144     // wacc [64][16] f       = 4096
#define A_OFF      266240     // A    [64][16][16] f   = 65536  -> 331776
#define ZERO_U4    20736      // 331776 bytes / 16
#define STARTG_OFF 331776     // startG [64] int
#define CURSG_OFF  332032     // cursorG[64] int
#define QS_OFF     332288     // qs [256] int          -> 333312
#define HP_OFF     333312     // hP [512][64] int      = 131072 -> 464384
#define ENDS_OFF   464384     // ends4 [256][2048] int = 2097152 -> 2561536
#define SG_OFF     2561536    // Sg [131072][16] f     = 8388608 -> 10950144
#define PK_OFF     10950144   // packed [2097152] u32  = 8388608 (sorted in place)

// ------- fused: zero accumulators + per-block e0-graph histogram (no atomics) --
__global__ __launch_bounds__(256) void k_histGZ(const int* __restrict__ e0,
                                                int* __restrict__ hP,
                                                uint4* __restrict__ zbase)
{
    __shared__ int h[64];
    const int t = threadIdx.x;
    const int blk = blockIdx.x;          // 512 blocks, 4096 edges each

    // zero Xs/wacc/A (20736 uint4 across 512 blocks)
    int zi = blk * 256 + t;
    if (zi < ZERO_U4) zbase[zi] = make_uint4(0u, 0u, 0u, 0u);

    if (t < 64) h[t] = 0;
    __syncthreads();
    size_t base = (size_t)blk * 4096;
    #pragma unroll
    for (int k = 0; k < 16; ++k) {
        int e = e0[base + k * 256 + t];
        atomicAdd(&h[e >> 11], 1);
    }
    __syncthreads();
    if (t < 64) hP[blk * 64 + t] = h[t];
}

// ------- reduce partials -> counts; scan -> startG/cursorG/qs ------------------
__global__ __launch_bounds__(1024) void k_prefixG(const int* __restrict__ hP,
                                                  int* __restrict__ startG,
                                                  int* __restrict__ cursorG,
                                                  int* __restrict__ qs)
{
    __shared__ int part[16 * 64];
    __shared__ int cg[64];
    const int t = threadIdx.x;
    const int g = t & 63;
    const int ch = t >> 6;               // 16 chunks of 32 blocks
    int s = 0;
    for (int b = ch * 32; b < ch * 32 + 32; ++b) s += hP[b * 64 + g];  // coalesced in g
    part[ch * 64 + g] = s;
    __syncthreads();
    if (t < 64) {
        int c = 0;
        #pragma unroll
        for (int i = 0; i < 16; ++i) c += part[i * 64 + t];
        cg[t] = c;
    }
    __syncthreads();
    if (t == 0) {
        int run = 0;
        for (int g2 = 0; g2 < 64; ++g2) {
            int n = cg[g2];
            startG[g2] = run; cursorG[g2] = run;
            int chunk = (n + 3) >> 2;
            #pragma unroll
            for (int q = 0; q < 4; ++q) qs[g2 * 4 + q] = run + min(q * chunk, n);
            run += n;
        }
    }
}

// ------- level-1 scatter: graph-grouped packed (e0l<<17 | e1) ------------------
__global__ __launch_bounds__(256) void k_scatterG(const int* __restrict__ e_,
                                                  int* __restrict__ cursorG,
                                                  unsigned* __restrict__ packed)
{
    __shared__ int h[64];
    __shared__ int gb[64];
    int t = threadIdx.x;
    if (t < 64) h[t] = 0;
    __syncthreads();
    size_t base = (size_t)blockIdx.x * 4096;     // 512 blocks
    int e0v[16], e1v[16], rk[16];
    #pragma unroll
    for (int k = 0; k < 16; ++k) {
        size_t i = base + k * 256 + t;
        e0v[k] = e_[i];
        e1v[k] = e_[BE + i];
        rk[k] = atomicAdd(&h[e0v[k] >> 11], 1);
    }
    __syncthreads();
    if (t < 64) gb[t] = atomicAdd(&cursorG[t], h[t]);
    __syncthreads();
    #pragma unroll
    for (int k = 0; k < 16; ++k) {
        int b = e0v[k] >> 11;
        packed[gb[b] + rk[k]] = ((unsigned)(e0v[k] & 2047) << 17) | (unsigned)e1v[k];
    }
}

// ---------------- node kernel: S = softmax(x@Wa+ba); accumulate Xs, w ----------
__global__ __launch_bounds__(128) void k_node(const float* __restrict__ x,
                                              const float* __restrict__ Wa,
                                              const float* __restrict__ ba,
                                              float* __restrict__ Sg,
                                              float* __restrict__ Xs,
                                              float* __restrict__ wacc)
{
    __shared__ __align__(16) float Xl[128 * 65];
    __shared__ __align__(16) float Sl[128 * 20];
    __shared__ float Wl[64 * 16];

    const int t = threadIdx.x;
    const int blk = blockIdx.x;       // 1024 blocks, 128 nodes each
    const int g = blk >> 4;

    const float4* xg4 = (const float4*)(x + (size_t)blk * 128 * 64);
    #pragma unroll
    for (int it = 0; it < 16; ++it) {
        int idx4 = it * 128 + t;
        float4 v = xg4[idx4];
        int node = idx4 >> 4;
        int c4 = (idx4 & 15) * 4;
        float* p = &Xl[node * 65 + c4];
        p[0] = v.x; p[1] = v.y; p[2] = v.z; p[3] = v.w;
    }
    for (int i = t; i < 1024; i += 128) Wl[i] = Wa[i];
    __syncthreads();

    float lg[16];
    #pragma unroll
    for (int m = 0; m < 16; ++m) lg[m] = ba[m];
    for (int c = 0; c < 64; ++c) {
        float xc = Xl[t * 65 + c];
        #pragma unroll
        for (int m = 0; m < 16; ++m) lg[m] += xc * Wl[c * 16 + m];
    }
    float mx = lg[0];
    #pragma unroll
    for (int m = 1; m < 16; ++m) mx = fmaxf(mx, lg[m]);
    float s[16]; float sum = 0.f;
    #pragma unroll
    for (int m = 0; m < 16; ++m) { s[m] = expf(lg[m] - mx); sum += s[m]; }
    float inv = 1.f / sum;
    #pragma unroll
    for (int m = 0; m < 16; ++m) s[m] *= inv;

    float* srow = Sg + ((size_t)blk * 128 + t) * 16;
    #pragma unroll
    for (int q = 0; q < 4; ++q) {
        float4 v4 = make_float4(s[q*4], s[q*4+1], s[q*4+2], s[q*4+3]);
        *(float4*)(srow + q * 4) = v4;
        *(float4*)(&Sl[t * 20 + q * 4]) = v4;
    }
    __syncthreads();

    const int c = t & 63;
    const int half = t >> 6;
    float acc[8];
    #pragma unroll
    for (int j = 0; j < 8; ++j) acc[j] = 0.f;
    for (int n = 0; n < 128; ++n) {
        float xv = Xl[n * 65 + c];
        float4 sa = *(const float4*)(&Sl[n * 20 + half * 8]);
        float4 sb = *(const float4*)(&Sl[n * 20 + half * 8 + 4]);
        acc[0] += sa.x * xv; acc[1] += sa.y * xv; acc[2] += sa.z * xv; acc[3] += sa.w * xv;
        acc[4] += sb.x * xv; acc[5] += sb.y * xv; acc[6] += sb.z * xv; acc[7] += sb.w * xv;
    }
    float* xsg = Xs + g * 1024;
    #pragma unroll
    for (int j = 0; j < 8; ++j) atomicAdd(&xsg[(half * 8 + j) * 64 + c], acc[j]);

    if (t < 16) {
        float ws_ = 0.f;
        for (int n = 0; n < 128; ++n) ws_ += Sl[n * 20 + t];
        atomicAdd(&wacc[g * 16 + t], ws_);
    }
}

// ---------------- level-2: LDS counting sort of each quarter-slab by e0l -------
#define SBUF_CAP 8704
__global__ __launch_bounds__(256) void k_sortL(unsigned* __restrict__ packed,
                                               const int* __restrict__ qs,
                                               int* __restrict__ ends4)
{
    __shared__ unsigned sbuf[SBUF_CAP];
    __shared__ unsigned sout[SBUF_CAP];
    __shared__ int h[2048];
    __shared__ int psum[256];
    const int t = threadIdx.x;
    const int Q = blockIdx.x;                 // g*4+q
    const int qlo = qs[Q];
    const int qhi = (Q == 255) ? BE : qs[Q + 1];
    const int nq = qhi - qlo;

    for (int i = t; i < 2048; i += 256) h[i] = 0;
    __syncthreads();
    for (int i = t; i < nq; i += 256) {
        unsigned u = packed[qlo + i];
        sbuf[i] = u;
        atomicAdd(&h[u >> 17], 1);
    }
    __syncthreads();

    int hl[8]; int s = 0;
    #pragma unroll
    for (int j = 0; j < 8; ++j) { hl[j] = h[t * 8 + j]; s += hl[j]; }
    psum[t] = s;
    __syncthreads();
    for (int off = 1; off < 256; off <<= 1) {
        int v = (t >= off) ? psum[t - off] : 0;
        __syncthreads();
        psum[t] += v;
        __syncthreads();
    }
    int run = psum[t] - s;
    int* ends = ends4 + (Q << 11);
    #pragma unroll
    for (int j = 0; j < 8; ++j) {
        int bin = t * 8 + j;
        int c = hl[j];
        h[bin] = run;
        run += c;
        ends[bin] = qlo + run;
    }
    __syncthreads();
    for (int i = t; i < nq; i += 256) {
        unsigned u = sbuf[i];
        int pos = atomicAdd(&h[u >> 17], 1);
        sout[pos] = u & 131071u;
    }
    __syncthreads();
    for (int i = t; i < nq; i += 256) packed[qlo + i] = sout[i];
}

// ---------------- edge kernel: AS per 64-node chunk (regs->LDS), then S^T@AS ---
__global__ __launch_bounds__(256) void k_edge(const unsigned* __restrict__ se1,
                                              const float* __restrict__ Sg,
                                              const int* __restrict__ ends4,
                                              const int* __restrict__ qs,
                                              float* __restrict__ A)
{
    __shared__ __align__(16) float ASl[64 * 16];
    const int t = threadIdx.x;
    const int blk = blockIdx.x;           // 2048 blocks, 64 nodes each
    const int g = blk >> 5;
    const int nbase = blk << 6;

    {
        const int qd = t >> 2;
        const int c4 = (t & 3) << 2;
        const int nl = (nbase & 2047) + qd;
        const float* __restrict__ SgB = Sg + c4;
        float a0 = 0.f, a1 = 0.f, a2 = 0.f, a3 = 0.f;
        float b0 = 0.f, b1 = 0.f, b2 = 0.f, b3 = 0.f;
        #pragma unroll
        for (int q = 0; q < 4; ++q) {
            const int Qb = (g << 2) + q;
            const int* __restrict__ ends = ends4 + (Qb << 11);
            int lo = nl ? ends[nl - 1] : qs[Qb];
            int hi = ends[nl];
            int i = lo;
            for (; i + 2 <= hi; i += 2) {
                unsigned ea = se1[i];
                unsigned eb = se1[i + 1];
                float4 va = *(const float4*)(SgB + ((size_t)ea << 4));
                float4 vb = *(const float4*)(SgB + ((size_t)eb << 4));
                a0 += va.x; a1 += va.y; a2 += va.z; a3 += va.w;
                b0 += vb.x; b1 += vb.y; b2 += vb.z; b3 += vb.w;
            }
            if (i < hi) {
                unsigned ea = se1[i];
                float4 va = *(const float4*)(SgB + ((size_t)ea << 4));
                a0 += va.x; a1 += va.y; a2 += va.z; a3 += va.w;
            }
        }
        *(float4*)(&ASl[qd * 16 + c4]) = make_float4(a0 + b0, a1 + b1, a2 + b2, a3 + b3);
    }
    __syncthreads();

    {
        const int m = t >> 4;
        const int k = t & 15;
        const float* __restrict__ SgM = Sg + ((size_t)nbase << 4) + m;
        float a = 0.f;
        #pragma unroll 4
        for (int i = 0; i < 64; ++i) {
            a += SgM[(size_t)i << 4] * ASl[i * 16 + k];
        }
        atomicAdd(&A[(g << 8) + t], a);
    }
}

// ------- fused epilogue: blocks 0..255 = x_out rows; blocks 256..259 = top-k ---
__global__ __launch_bounds__(256) void k_xt(const float* __restrict__ Xs,
                                            const float* __restrict__ wacc,
                                            const float* __restrict__ We,
                                            const float* __restrict__ be,
                                            const float* __restrict__ A,
                                            float* __restrict__ out)
{
    const int t = threadIdx.x;
    const int blk = blockIdx.x;
    if (blk < 256) {
        int lane = t & 63;
        int row = blk * 4 + (t >> 6);
        const float* xs = Xs + row * 64;
        float w = wacc[row];
        float val;
        if (lane < 3) {
            val = xs[lane] / fmaxf(w, 1e-10f);
        } else {
            int c2 = lane - 3;
            float accv = w * be[c2];
            for (int cc = 0; cc < 64; ++cc) accv += xs[cc] * We[cc * 61 + c2];
            val = accv;
        }
        out[row * 64 + lane] = val;
    } else {
        int r = (blk - 256) * 256 + t;    // 0..1023
        float v[16];
        #pragma unroll
        for (int i = 0; i < 16; ++i) v[i] = A[r * 16 + i];
        float* e0o = out + 65536;
        float* e1o = out + 65536 + 4096;
        float* bo  = out + 65536 + 8192;
        unsigned mask = 0;
        #pragma unroll
        for (int rep = 0; rep < 4; ++rep) {
            float best = -3.4e38f; int bi = 0;
            #pragma unroll
            for (int i = 0; i < 16; ++i) {
                bool ok = (((mask >> i) & 1u) == 0u) && (v[i] > best);
                if (ok) { best = v[i]; bi = i; }
            }
            mask |= (1u << bi);
            e0o[r * 4 + rep] = (float)r;
            e1o[r * 4 + rep] = (float)((r & ~15) + bi);
        }
        bo[r] = (float)(r >> 4);
    }
}

extern "C" void kernel_launch(void* const* d_in, const int* in_sizes, int n_in,
                              void* d_out, int out_size, void* d_ws, size_t ws_size,
                              hipStream_t stream)
{
    const float* x  = (const float*)d_in[0];
    const int*   e  = (const int*)d_in[1];
    const float* Wa = (const float*)d_in[3];
    const float* ba = (const float*)d_in[4];
    const float* We = (const float*)d_in[5];
    const float* be = (const float*)d_in[6];

    char* ws = (char*)d_ws;
    float* Xs     = (float*)(ws + XS_OFF);
    float* wacc   = (float*)(ws + WACC_OFF);
    float* A      = (float*)(ws + A_OFF);
    int*   startG = (int*)(ws + STARTG_OFF);
    int*   cursG  = (int*)(ws + CURSG_OFF);
    int*   qs     = (int*)(ws + QS_OFF);
    int*   hP     = (int*)(ws + HP_OFF);
    int*   ends4  = (int*)(ws + ENDS_OFF);
    float* Sg     = (float*)(ws + SG_OFF);
    unsigned* packed = (unsigned*)(ws + PK_OFF);

    k_histGZ  <<<512, 256, 0, stream>>>(e, hP, (uint4*)ws);
    k_prefixG <<<1, 1024, 0, stream>>>(hP, startG, cursG, qs);
    k_scatterG<<<512, 256, 0, stream>>>(e, cursG, packed);
    k_node    <<<1024, 128, 0, stream>>>(x, Wa, ba, Sg, Xs, wacc);
    k_sortL   <<<256, 256, 0, stream>>>(packed, qs, ends4);
    k_edge    <<<2048, 256, 0, stream>>>(packed, Sg, ends4, qs, A);
    k_xt      <<<260, 256, 0, stream>>>(Xs, wacc, We, be, A, (float*)d_out);
}